// Round 14
// baseline (636.051 us; speedup 1.0000x reference)
//
#include <hip/hip_runtime.h>

#define B_   32
#define C_   256
#define N_   1024
#define L_   12
#define H_   8
#define DK_  32
#define NL_  12288
#define CNL_ 3145728
#define ND_  32768
#define HLN_ 98304
#define SCALE_ 0.17677669529663687f

typedef _Float16 half8 __attribute__((ext_vector_type(8)));
typedef _Float16 half4 __attribute__((ext_vector_type(4)));
typedef float f32x4 __attribute__((ext_vector_type(4)));

__device__ __forceinline__ int div12(int s) { return (int)(((unsigned)s * 43691u) >> 19); }

// ---- P: one-time fp32 -> fp16 weight conversion into FRAGMENT-ORDER layout --
__global__ __launch_bounds__(256) void k_prep(const float* __restrict__ wq,
    const float* __restrict__ wv, const float* __restrict__ cw,
    _Float16* __restrict__ Wfrag, _Float16* __restrict__ Cfrag) {
    const int gid = blockIdx.x * 256 + threadIdx.x;   // grid 96 -> 24576
    if (gid < 16384) {
        const int kb = gid >> 11, r = gid & 2047;
        const int mt = r >> 6, o = (r >> 4) & 3, lo = r & 15;
        const int m = mt * 16 + lo;
        const float* src = (m < 256 ? wq + (size_t)m * 256 : wv + (size_t)(m - 256) * 256)
                           + kb * 32 + o * 8;
        f32x4 a0 = *(const f32x4*)src, a1 = *(const f32x4*)(src + 4);
        half8 h;
#pragma unroll
        for (int i = 0; i < 4; ++i) { h[i] = (_Float16)a0[i]; h[4 + i] = (_Float16)a1[i]; }
        *(half8*)(Wfrag + (size_t)gid * 8) = h;
    } else {
        const int c = gid - 16384;                    // < 8192
        const int kb = c >> 10, r = c & 1023;
        const int mt = r >> 6, o = (r >> 4) & 3, lo = r & 15;
        const int m = mt * 16 + lo;
        const float* src = cw + (size_t)m * 256 + kb * 32 + o * 8;
        f32x4 a0 = *(const f32x4*)src, a1 = *(const f32x4*)(src + 4);
        half8 h;
#pragma unroll
        for (int i = 0; i < 4; ++i) { h[i] = (_Float16)a0[i]; h[4 + i] = (_Float16)a1[i]; }
        *(half8*)(Cfrag + (size_t)c * 8) = h;
    }
}

// ---- K0: softmax over DK -> ksT[hl][x][n]; LDS transpose, coalesced stores --
__global__ __launch_bounds__(256) void k_key_softmax(const float* __restrict__ sb,
                                                     _Float16* __restrict__ ksT) {
    __shared__ _Float16 smT[32 * 260];
    const int t = threadIdx.x;
    const int row = blockIdx.x * 256 + t;
    const f32x4* src = (const f32x4*)(sb + (size_t)row * DK_);
    float v[DK_];
#pragma unroll
    for (int i = 0; i < 8; i++) {
        f32x4 t4 = src[i];
        v[4*i+0] = t4[0]; v[4*i+1] = t4[1]; v[4*i+2] = t4[2]; v[4*i+3] = t4[3];
    }
    float m = v[0];
#pragma unroll
    for (int i = 1; i < DK_; i++) m = fmaxf(m, v[i]);
    float s = 0.f;
#pragma unroll
    for (int i = 0; i < DK_; i++) { v[i] = __expf((v[i] - m) * SCALE_); s += v[i]; }
    const float inv = 1.f / s;
#pragma unroll
    for (int i = 0; i < DK_; i++) smT[i * 260 + t] = (_Float16)(v[i] * inv);
    __syncthreads();
    const int x = t >> 3, off = (t & 7) * 32;
    const int base = blockIdx.x * 256;
    const int hl = base >> 10, nb = base & 1023;
    _Float16* dst = ksT + (size_t)hl * ND_ + (size_t)x * 1024 + nb + off;
    const _Float16* srcT = &smT[x * 260 + off];
#pragma unroll
    for (int k = 0; k < 4; ++k)
        *(half8*)(dst + k * 8) = *(const half8*)(srcT + k * 8);
}

// ------- K1 (R11-best): merged q+v conv; M=512, W in REGISTERS, S=32/iter ---
__global__ __launch_bounds__(512, 2) void k_conv_qv(
    const float* __restrict__ x, const _Float16* __restrict__ Wfrag,
    const float* __restrict__ bqp, const float* __restrict__ bvp,
    _Float16* __restrict__ qh, _Float16* __restrict__ vh)
{
    __shared__ __align__(16) _Float16 Xl[2][8192];

    const int t = threadIdx.x;
    const int sgrp = blockIdx.x;            // 0..15
    const int b = blockIdx.y;
    const int sbase = sgrp * 768;
    const int w = t >> 6, lane = t & 63;
    const int lo = lane & 15, hi = lane >> 4;

    half8 af[8][4];
#pragma unroll
    for (int kb = 0; kb < 8; ++kb)
#pragma unroll
        for (int m = 0; m < 4; ++m)
            af[kb][m] = *(const half8*)(Wfrag +
                ((size_t)kb*2048 + (size_t)(w*4 + m)*64 + lane) * 8);

    const float* bsel = (w >= 4) ? bvp : bqp;
    f32x4 bb[4];
#pragma unroll
    for (int m = 0; m < 4; ++m)
        bb[m] = *(const f32x4*)(bsel + ((w & 3)*4 + m)*16 + hi*4);

    const int xch = t >> 1, xsh = (t & 1) * 8;
    const int g = xch >> 3, elem = xch & 7;
    const int wb = g*128 + elem;
    const int sx = xsh ^ ((g & 7) << 1) ^ (xsh >> 3);
    const float* px = x + (size_t)b * CNL_ + (size_t)xch * NL_ + sbase + xsh;

    const int base_r = hi*128 + ((lo ^ (hi*2) ^ ((lo & 8) >> 3)) << 3);

    f32x4 c0 = *(const f32x4*)px,        c1 = *(const f32x4*)(px + 4);
    f32x4 c2 = *(const f32x4*)(px + 16), c3 = *(const f32x4*)(px + 20);
#pragma unroll
    for (int k = 0; k < 4; ++k) {
        Xl[0][wb + (((k  ) ^ sx) << 3)]        = (_Float16)c0[k];
        Xl[0][wb + (((k+4) ^ sx) << 3)]        = (_Float16)c1[k];
        Xl[0][4096 + wb + (((k  ) ^ sx) << 3)] = (_Float16)c2[k];
        Xl[0][4096 + wb + (((k+4) ^ sx) << 3)] = (_Float16)c3[k];
    }
    c0 = *(const f32x4*)(px + 32); c1 = *(const f32x4*)(px + 36);
    c2 = *(const f32x4*)(px + 48); c3 = *(const f32x4*)(px + 52);

    for (int i = 0; i < 24; ++i) {
        asm volatile("s_waitcnt lgkmcnt(0)" ::: "memory");
        __builtin_amdgcn_s_barrier();
        __builtin_amdgcn_sched_barrier(0);
        const _Float16* Xc = Xl[i & 1];
        f32x4 acc[4][2] = {};
#pragma unroll
        for (int kb = 0; kb < 8; ++kb) {
            const int ro = kb*512 + (base_r ^ ((kb & 1) << 6));
            half8 bf0 = *(const half8*)&Xc[ro];
            half8 bf1 = *(const half8*)&Xc[4096 + ro];
#pragma unroll
            for (int m = 0; m < 4; ++m) {
                acc[m][0] = __builtin_amdgcn_mfma_f32_16x16x32_f16(af[kb][m], bf0, acc[m][0], 0, 0, 0);
                acc[m][1] = __builtin_amdgcn_mfma_f32_16x16x32_f16(af[kb][m], bf1, acc[m][1], 0, 0, 0);
            }
        }
        if (i < 23) {
            _Float16* Xn = Xl[(i + 1) & 1];
#pragma unroll
            for (int k = 0; k < 4; ++k) {
                Xn[wb + (((k  ) ^ sx) << 3)]        = (_Float16)c0[k];
                Xn[wb + (((k+4) ^ sx) << 3)]        = (_Float16)c1[k];
                Xn[4096 + wb + (((k  ) ^ sx) << 3)] = (_Float16)c2[k];
                Xn[4096 + wb + (((k+4) ^ sx) << 3)] = (_Float16)c3[k];
            }
            if (i < 22) {
                const float* p = px + (size_t)(i + 2) * 32;
                c0 = *(const f32x4*)p;        c1 = *(const f32x4*)(p + 4);
                c2 = *(const f32x4*)(p + 16); c3 = *(const f32x4*)(p + 20);
            }
        }
#pragma unroll
        for (int u = 0; u < 2; ++u) {
            const int sg = sbase + i*32 + u*16 + lo;
            const int n = div12(sg), l = sg - n*12;
#pragma unroll
            for (int m = 0; m < 4; ++m) {
                const int o = (w*4 + m)*16 + hi*4;
                const int ol = o & 255;
                _Float16* dst0 = (w >= 4) ? vh : qh;
                half4 hh;
#pragma unroll
                for (int r = 0; r < 4; ++r) hh[r] = (_Float16)fmaxf(acc[m][u][r] + bb[m][r], 0.f);
                *(half4*)(dst0 + ((size_t)(b*8 + (ol >> 5))*12 + l)*ND_ + (size_t)n*32 + (ol & 31)) = hh;
            }
        }
    }
}

// ---- K2: kvT[b,h,l][y][x] = sum_n V[n][y]*K[n][x] via MFMA ------------------
__global__ __launch_bounds__(256) void k_kv(const _Float16* __restrict__ ksT,
    const _Float16* __restrict__ v, _Float16* __restrict__ kvT) {
    __shared__ float red[4096];
    const int bid = blockIdx.x;            // (b*8+h)*12 + l
    const int bh = bid / 12;
    const int l  = bid - bh * 12;
    const int h  = bh & 7;
    const int t = threadIdx.x, w = t >> 6, lane = t & 63;
    const int lo = lane & 15, hi = lane >> 4;
    const _Float16* vb  = v   + (size_t)bid * ND_;
    const _Float16* ksb = ksT + (size_t)(h*12 + l) * ND_;

    f32x4 acc[2][2] = {};
#pragma unroll 2
    for (int c = 0; c < 8; ++c) {
        const int n0 = w*256 + c*32 + hi*8;
        half8 a0, a1;
#pragma unroll
        for (int j = 0; j < 8; ++j) {
            a0[j] = vb[(size_t)(n0 + j)*32 + lo];
            a1[j] = vb[(size_t)(n0 + j)*32 + 16 + lo];
        }
        half8 b0 = *(const half8*)(ksb + (size_t)lo*1024 + n0);
        half8 b1 = *(const half8*)(ksb + (size_t)(16 + lo)*1024 + n0);
        acc[0][0] = __builtin_amdgcn_mfma_f32_16x16x32_f16(a0, b0, acc[0][0], 0, 0, 0);
        acc[0][1] = __builtin_amdgcn_mfma_f32_16x16x32_f16(a0, b1, acc[0][1], 0, 0, 0);
        acc[1][0] = __builtin_amdgcn_mfma_f32_16x16x32_f16(a1, b0, acc[1][0], 0, 0, 0);
        acc[1][1] = __builtin_amdgcn_mfma_f32_16x16x32_f16(a1, b1, acc[1][1], 0, 0, 0);
    }
#pragma unroll
    for (int m = 0; m < 2; ++m)
#pragma unroll
        for (int xm = 0; xm < 2; ++xm)
#pragma unroll
            for (int reg = 0; reg < 4; ++reg)
                red[w*1024 + (m*16 + hi*4 + reg)*32 + xm*16 + lo] = acc[m][xm][reg];
    __syncthreads();
    const int e = t * 4;
    f32x4 s = *(const f32x4*)&red[e];
    s += *(const f32x4*)&red[1024 + e];
    s += *(const f32x4*)&red[2048 + e];
    s += *(const f32x4*)&red[3072 + e];
    half4 o;
#pragma unroll
    for (int i = 0; i < 4; ++i) o[i] = (_Float16)s[i];
    *(half4*)(kvT + (size_t)bid * 1024 + e) = o;
}

// ---- K3: fused softmax(q)@kvT + final conv; 2 heads/phase, 8-wave PV -------
// 5 phases: phase p does PV(head-pair p) [p<4] and conv(pair p-1) [p>=1].
// PV: 24 (head,l) units split 3 per wave. Xt[2 buf][2 head][3072].
__global__ __launch_bounds__(512, 2) void k_conv_out(
    const _Float16* __restrict__ q, const _Float16* __restrict__ kvw,
    const _Float16* __restrict__ Cfrag, const float* __restrict__ cbp,
    float* __restrict__ out) {
    __shared__ __align__(16) _Float16 Xt[2][2][3072];
    __shared__ float Cb[256];

    const int t = threadIdx.x;
    const int bx = blockIdx.x, b = blockIdx.y;
    const int s0 = bx * 96;
    const int n0 = bx * 8;
    const int w = t >> 6, lane = t & 63;
    const int lo = lane & 15, hi = lane >> 4;
    if (t < 64) *(f32x4*)&Cb[t*4] = *(const f32x4*)(cbp + t*4);

    f32x4 acc[4][3] = {};

    const int qrow = n0 + (lo & 7);
    const float rowmask = (lo < 8) ? 1.f : 0.f;
    const size_t hstep = (size_t)12 * ND_;
    const _Float16* qb_b = q + (size_t)b * 8 * hstep;
    const _Float16* kv_b = kvw + (size_t)b * 98304;

    // wave w owns PV units u = w*3 + s (s=0..2); unit -> (hp = u>=12, li = u%12)
    int uhp[3], uli[3];
#pragma unroll
    for (int s = 0; s < 3; ++s) {
        const int u = w*3 + s;
        uhp[s] = (u >= 12) ? 1 : 0;
        uli[s] = u - uhp[s]*12;
    }

    half8 hq[3];
#pragma unroll
    for (int s = 0; s < 3; ++s)
        hq[s] = *(const half8*)(qb_b + (size_t)(0*2 + uhp[s])*hstep
                                + (size_t)uli[s]*ND_ + (size_t)qrow*32 + hi*8);

    for (int p = 0; p <= 4; ++p) {
        // ---- PV(pair p): all 8 waves, 3 units each -> Xt[p&1][hp] ----
        if (p < 4) {
            half8 nq[3];
#pragma unroll
            for (int s = 0; s < 3; ++s) nq[s] = hq[s];
            if (p < 3) {
#pragma unroll
                for (int s = 0; s < 3; ++s)
                    nq[s] = *(const half8*)(qb_b + (size_t)((p+1)*2 + uhp[s])*hstep
                                            + (size_t)uli[s]*ND_ + (size_t)qrow*32 + hi*8);
            }
#pragma unroll
            for (int s = 0; s < 3; ++s) {
                const half8 hqv = hq[s];
                const int li = uli[s];
                const _Float16* kvh = kv_b + (size_t)(p*2 + uhp[s]) * 12288;
                _Float16* Xd = Xt[p & 1][uhp[s]];
                float qv[8];
#pragma unroll
                for (int i = 0; i < 8; ++i) qv[i] = (float)hqv[i];
                float m8 = fmaxf(fmaxf(fmaxf(qv[0], qv[1]), fmaxf(qv[2], qv[3])),
                                 fmaxf(fmaxf(qv[4], qv[5]), fmaxf(qv[6], qv[7])));
                m8 = fmaxf(m8, __shfl_xor(m8, 16));
                m8 = fmaxf(m8, __shfl_xor(m8, 32));
                const float mS = m8 * SCALE_;
                float ex[8]; float ssum = 0.f;
#pragma unroll
                for (int i = 0; i < 8; ++i) { ex[i] = __expf(qv[i]*SCALE_ - mS); ssum += ex[i]; }
                ssum += __shfl_xor(ssum, 16);
                ssum += __shfl_xor(ssum, 32);
                const float pin = rowmask / ssum;
                half8 afp;
#pragma unroll
                for (int i = 0; i < 8; ++i) afp[i] = (_Float16)(ex[i] * pin);
                const half8 b0 = *(const half8*)(kvh + li*1024 + lo*32 + hi*8);
                const half8 b1 = *(const half8*)(kvh + li*1024 + (16+lo)*32 + hi*8);
                f32x4 d0 = {}, d1 = {};
                d0 = __builtin_amdgcn_mfma_f32_16x16x32_f16(afp, b0, d0, 0, 0, 0);
                d1 = __builtin_amdgcn_mfma_f32_16x16x32_f16(afp, b1, d1, 0, 0, 0);
                if (hi < 2) {
#pragma unroll
                    for (int reg = 0; reg < 4; ++reg) {
                        const int sr = (hi*4 + reg)*12 + li;
                        const int cb_ = (sr >> 4)*64 + (sr & 15);
                        Xd[(cb_ + (lo >> 3)*16)*8 + (lo & 7)]       = (_Float16)d0[reg];
                        Xd[(cb_ + (2 + (lo >> 3))*16)*8 + (lo & 7)] = (_Float16)d1[reg];
                    }
                }
            }
#pragma unroll
            for (int s = 0; s < 3; ++s) hq[s] = nq[s];
        }
        // ---- conv(pair p-1): both heads from Xt[(p-1)&1][*] ----
        if (p >= 1) {
#pragma unroll
            for (int h01 = 0; h01 < 2; ++h01) {
                const _Float16* Wk = Cfrag + (size_t)((p-1)*2 + h01) * 8192;
                const _Float16* Xc = Xt[(p - 1) & 1][h01];
                half8 af2[4], bf[3];
#pragma unroll
                for (int m = 0; m < 4; ++m)
                    af2[m] = *(const half8*)(Wk + ((((w>>1)*4 + m)*4 + hi)*16 + lo) * 8);
#pragma unroll
                for (int sf = 0; sf < 3; ++sf)
                    bf[sf] = *(const half8*)&Xc[((((w&1)*3 + sf)*4 + hi)*16 + lo) * 8];
#pragma unroll
                for (int m = 0; m < 4; ++m)
#pragma unroll
                    for (int sf = 0; sf < 3; ++sf)
                        acc[m][sf] = __builtin_amdgcn_mfma_f32_16x16x32_f16(af2[m], bf[sf], acc[m][sf], 0, 0, 0);
            }
        }
        asm volatile("s_waitcnt lgkmcnt(0)" ::: "memory");
        __builtin_amdgcn_s_barrier();
        __builtin_amdgcn_sched_barrier(0);
    }

#pragma unroll
    for (int m = 0; m < 4; ++m) {
        const int o = (w>>1)*64 + m*16 + hi*4;
        const f32x4 bb = *(const f32x4*)&Cb[o];
#pragma unroll
        for (int sf = 0; sf < 3; ++sf) {
            const int s = s0 + (w&1)*48 + sf*16 + lo;
            float* dst = out + (size_t)(b*256 + o)*12288 + s;
#pragma unroll
            for (int i = 0; i < 4; ++i)
                dst[(size_t)i * 12288] = fmaxf(acc[m][sf][i] + bb[i], 0.f);
        }
    }
}

extern "C" void kernel_launch(void* const* d_in, const int* in_sizes, int n_in,
                              void* d_out, int out_size, void* d_ws, size_t ws_size,
                              hipStream_t stream) {
    const float* input = (const float*)d_in[0];
    const float* q_w   = (const float*)d_in[1];
    const float* q_b   = (const float*)d_in[2];
    const float* v_w   = (const float*)d_in[3];
    const float* v_b   = (const float*)d_in[4];
    const float* c_w   = (const float*)d_in[5];
    const float* c_b   = (const float*)d_in[6];
    const float* s_bank= (const float*)d_in[7];
    float* out = (float*)d_out;

    char* ws = (char*)d_ws;
    _Float16* ks16 = (_Float16*)ws;                          // 6,291,456 B (ksT)
    _Float16* qh   = (_Float16*)(ws + 6291456);              // 201,326,592 B
    _Float16* vh   = qh + (size_t)100663296;                 // 201,326,592 B
    _Float16* kvT  = vh + (size_t)100663296;                 // 6,291,456 B
    _Float16* Wfrag= kvT + (size_t)3145728;                  // 262,144 B
    _Float16* Cfrag= Wfrag + (size_t)131072;                 // 131,072 B

    k_prep<<<dim3(96), dim3(256), 0, stream>>>(q_w, v_w, c_w, Wfrag, Cfrag);
    k_key_softmax<<<dim3(HLN_ / 256), dim3(256), 0, stream>>>(s_bank, ks16);
    k_conv_qv<<<dim3(16, 32), dim3(512), 0, stream>>>(input, Wfrag, q_b, v_b, qh, vh);
    k_kv<<<dim3(B_ * H_ * L_), dim3(256), 0, stream>>>(ks16, vh, kvT);
    k_conv_out<<<dim3(128, 32), dim3(512), 0, stream>>>(qh, kvT, Cfrag, c_b, out);
}

// Round 15
// 562.260 us; speedup vs baseline: 1.1312x; 1.1312x over previous
//
#include <hip/hip_runtime.h>

#define B_   32
#define C_   256
#define N_   1024
#define L_   12
#define H_   8
#define DK_  32
#define NL_  12288
#define CNL_ 3145728
#define ND_  32768
#define HLN_ 98304
#define SCALE_ 0.17677669529663687f

typedef _Float16 half8 __attribute__((ext_vector_type(8)));
typedef _Float16 half4 __attribute__((ext_vector_type(4)));
typedef float f32x4 __attribute__((ext_vector_type(4)));

__device__ __forceinline__ int div12(int s) { return (int)(((unsigned)s * 43691u) >> 19); }
// bank-spreading chunk swizzle for conv_out's Xt (bijective within 64-chunk rows)
__device__ __forceinline__ int fsw(int c) { return c ^ (((c >> 4) & 1) << 2) ^ ((c >> 6) & 3); }

// ---- P: one-time fp32 -> fp16 weight conversion into FRAGMENT-ORDER layout --
__global__ __launch_bounds__(256) void k_prep(const float* __restrict__ wq,
    const float* __restrict__ wv, const float* __restrict__ cw,
    _Float16* __restrict__ Wfrag, _Float16* __restrict__ Cfrag) {
    const int gid = blockIdx.x * 256 + threadIdx.x;   // grid 96 -> 24576
    if (gid < 16384) {
        const int kb = gid >> 11, r = gid & 2047;
        const int mt = r >> 6, o = (r >> 4) & 3, lo = r & 15;
        const int m = mt * 16 + lo;
        const float* src = (m < 256 ? wq + (size_t)m * 256 : wv + (size_t)(m - 256) * 256)
                           + kb * 32 + o * 8;
        f32x4 a0 = *(const f32x4*)src, a1 = *(const f32x4*)(src + 4);
        half8 h;
#pragma unroll
        for (int i = 0; i < 4; ++i) { h[i] = (_Float16)a0[i]; h[4 + i] = (_Float16)a1[i]; }
        *(half8*)(Wfrag + (size_t)gid * 8) = h;
    } else {
        const int c = gid - 16384;                    // < 8192
        const int kb = c >> 10, r = c & 1023;
        const int mt = r >> 6, o = (r >> 4) & 3, lo = r & 15;
        const int m = mt * 16 + lo;
        const float* src = cw + (size_t)m * 256 + kb * 32 + o * 8;
        f32x4 a0 = *(const f32x4*)src, a1 = *(const f32x4*)(src + 4);
        half8 h;
#pragma unroll
        for (int i = 0; i < 4; ++i) { h[i] = (_Float16)a0[i]; h[4 + i] = (_Float16)a1[i]; }
        *(half8*)(Cfrag + (size_t)c * 8) = h;
    }
}

// ---- K0: softmax over DK -> ksT[hl][x][n]; LDS transpose, coalesced stores --
__global__ __launch_bounds__(256) void k_key_softmax(const float* __restrict__ sb,
                                                     _Float16* __restrict__ ksT) {
    __shared__ _Float16 smT[32 * 260];
    const int t = threadIdx.x;
    const int row = blockIdx.x * 256 + t;
    const f32x4* src = (const f32x4*)(sb + (size_t)row * DK_);
    float v[DK_];
#pragma unroll
    for (int i = 0; i < 8; i++) {
        f32x4 t4 = src[i];
        v[4*i+0] = t4[0]; v[4*i+1] = t4[1]; v[4*i+2] = t4[2]; v[4*i+3] = t4[3];
    }
    float m = v[0];
#pragma unroll
    for (int i = 1; i < DK_; i++) m = fmaxf(m, v[i]);
    float s = 0.f;
#pragma unroll
    for (int i = 0; i < DK_; i++) { v[i] = __expf((v[i] - m) * SCALE_); s += v[i]; }
    const float inv = 1.f / s;
#pragma unroll
    for (int i = 0; i < DK_; i++) smT[i * 260 + t] = (_Float16)(v[i] * inv);
    __syncthreads();
    const int x = t >> 3, off = (t & 7) * 32;
    const int base = blockIdx.x * 256;
    const int hl = base >> 10, nb = base & 1023;
    _Float16* dst = ksT + (size_t)hl * ND_ + (size_t)x * 1024 + nb + off;
    const _Float16* srcT = &smT[x * 260 + off];
#pragma unroll
    for (int k = 0; k < 4; ++k)
        *(half8*)(dst + k * 8) = *(const half8*)(srcT + k * 8);
}

// ------- K1 (R11-best): merged q+v conv; M=512, W in REGISTERS, S=32/iter ---
__global__ __launch_bounds__(512, 2) void k_conv_qv(
    const float* __restrict__ x, const _Float16* __restrict__ Wfrag,
    const float* __restrict__ bqp, const float* __restrict__ bvp,
    _Float16* __restrict__ qh, _Float16* __restrict__ vh)
{
    __shared__ __align__(16) _Float16 Xl[2][8192];

    const int t = threadIdx.x;
    const int sgrp = blockIdx.x;            // 0..15
    const int b = blockIdx.y;
    const int sbase = sgrp * 768;
    const int w = t >> 6, lane = t & 63;
    const int lo = lane & 15, hi = lane >> 4;

    half8 af[8][4];
#pragma unroll
    for (int kb = 0; kb < 8; ++kb)
#pragma unroll
        for (int m = 0; m < 4; ++m)
            af[kb][m] = *(const half8*)(Wfrag +
                ((size_t)kb*2048 + (size_t)(w*4 + m)*64 + lane) * 8);

    const float* bsel = (w >= 4) ? bvp : bqp;
    f32x4 bb[4];
#pragma unroll
    for (int m = 0; m < 4; ++m)
        bb[m] = *(const f32x4*)(bsel + ((w & 3)*4 + m)*16 + hi*4);

    const int xch = t >> 1, xsh = (t & 1) * 8;
    const int g = xch >> 3, elem = xch & 7;
    const int wb = g*128 + elem;
    const int sx = xsh ^ ((g & 7) << 1) ^ (xsh >> 3);
    const float* px = x + (size_t)b * CNL_ + (size_t)xch * NL_ + sbase + xsh;

    const int base_r = hi*128 + ((lo ^ (hi*2) ^ ((lo & 8) >> 3)) << 3);

    f32x4 c0 = *(const f32x4*)px,        c1 = *(const f32x4*)(px + 4);
    f32x4 c2 = *(const f32x4*)(px + 16), c3 = *(const f32x4*)(px + 20);
#pragma unroll
    for (int k = 0; k < 4; ++k) {
        Xl[0][wb + (((k  ) ^ sx) << 3)]        = (_Float16)c0[k];
        Xl[0][wb + (((k+4) ^ sx) << 3)]        = (_Float16)c1[k];
        Xl[0][4096 + wb + (((k  ) ^ sx) << 3)] = (_Float16)c2[k];
        Xl[0][4096 + wb + (((k+4) ^ sx) << 3)] = (_Float16)c3[k];
    }
    c0 = *(const f32x4*)(px + 32); c1 = *(const f32x4*)(px + 36);
    c2 = *(const f32x4*)(px + 48); c3 = *(const f32x4*)(px + 52);

    for (int i = 0; i < 24; ++i) {
        asm volatile("s_waitcnt lgkmcnt(0)" ::: "memory");
        __builtin_amdgcn_s_barrier();
        __builtin_amdgcn_sched_barrier(0);
        const _Float16* Xc = Xl[i & 1];
        f32x4 acc[4][2] = {};
#pragma unroll
        for (int kb = 0; kb < 8; ++kb) {
            const int ro = kb*512 + (base_r ^ ((kb & 1) << 6));
            half8 bf0 = *(const half8*)&Xc[ro];
            half8 bf1 = *(const half8*)&Xc[4096 + ro];
#pragma unroll
            for (int m = 0; m < 4; ++m) {
                acc[m][0] = __builtin_amdgcn_mfma_f32_16x16x32_f16(af[kb][m], bf0, acc[m][0], 0, 0, 0);
                acc[m][1] = __builtin_amdgcn_mfma_f32_16x16x32_f16(af[kb][m], bf1, acc[m][1], 0, 0, 0);
            }
        }
        if (i < 23) {
            _Float16* Xn = Xl[(i + 1) & 1];
#pragma unroll
            for (int k = 0; k < 4; ++k) {
                Xn[wb + (((k  ) ^ sx) << 3)]        = (_Float16)c0[k];
                Xn[wb + (((k+4) ^ sx) << 3)]        = (_Float16)c1[k];
                Xn[4096 + wb + (((k  ) ^ sx) << 3)] = (_Float16)c2[k];
                Xn[4096 + wb + (((k+4) ^ sx) << 3)] = (_Float16)c3[k];
            }
            if (i < 22) {
                const float* p = px + (size_t)(i + 2) * 32;
                c0 = *(const f32x4*)p;        c1 = *(const f32x4*)(p + 4);
                c2 = *(const f32x4*)(p + 16); c3 = *(const f32x4*)(p + 20);
            }
        }
#pragma unroll
        for (int u = 0; u < 2; ++u) {
            const int sg = sbase + i*32 + u*16 + lo;
            const int n = div12(sg), l = sg - n*12;
#pragma unroll
            for (int m = 0; m < 4; ++m) {
                const int o = (w*4 + m)*16 + hi*4;
                const int ol = o & 255;
                _Float16* dst0 = (w >= 4) ? vh : qh;
                half4 hh;
#pragma unroll
                for (int r = 0; r < 4; ++r) hh[r] = (_Float16)fmaxf(acc[m][u][r] + bb[m][r], 0.f);
                *(half4*)(dst0 + ((size_t)(b*8 + (ol >> 5))*12 + l)*ND_ + (size_t)n*32 + (ol & 31)) = hh;
            }
        }
    }
}

// ---- K2: kvT[b,h,l][y][x] = sum_n V[n][y]*K[n][x] via MFMA ------------------
__global__ __launch_bounds__(256) void k_kv(const _Float16* __restrict__ ksT,
    const _Float16* __restrict__ v, _Float16* __restrict__ kvT) {
    __shared__ float red[4096];
    const int bid = blockIdx.x;            // (b*8+h)*12 + l
    const int bh = bid / 12;
    const int l  = bid - bh * 12;
    const int h  = bh & 7;
    const int t = threadIdx.x, w = t >> 6, lane = t & 63;
    const int lo = lane & 15, hi = lane >> 4;
    const _Float16* vb  = v   + (size_t)bid * ND_;
    const _Float16* ksb = ksT + (size_t)(h*12 + l) * ND_;

    f32x4 acc[2][2] = {};
#pragma unroll 2
    for (int c = 0; c < 8; ++c) {
        const int n0 = w*256 + c*32 + hi*8;
        half8 a0, a1;
#pragma unroll
        for (int j = 0; j < 8; ++j) {
            a0[j] = vb[(size_t)(n0 + j)*32 + lo];
            a1[j] = vb[(size_t)(n0 + j)*32 + 16 + lo];
        }
        half8 b0 = *(const half8*)(ksb + (size_t)lo*1024 + n0);
        half8 b1 = *(const half8*)(ksb + (size_t)(16 + lo)*1024 + n0);
        acc[0][0] = __builtin_amdgcn_mfma_f32_16x16x32_f16(a0, b0, acc[0][0], 0, 0, 0);
        acc[0][1] = __builtin_amdgcn_mfma_f32_16x16x32_f16(a0, b1, acc[0][1], 0, 0, 0);
        acc[1][0] = __builtin_amdgcn_mfma_f32_16x16x32_f16(a1, b0, acc[1][0], 0, 0, 0);
        acc[1][1] = __builtin_amdgcn_mfma_f32_16x16x32_f16(a1, b1, acc[1][1], 0, 0, 0);
    }
#pragma unroll
    for (int m = 0; m < 2; ++m)
#pragma unroll
        for (int xm = 0; xm < 2; ++xm)
#pragma unroll
            for (int reg = 0; reg < 4; ++reg)
                red[w*1024 + (m*16 + hi*4 + reg)*32 + xm*16 + lo] = acc[m][xm][reg];
    __syncthreads();
    const int e = t * 4;
    f32x4 s = *(const f32x4*)&red[e];
    s += *(const f32x4*)&red[1024 + e];
    s += *(const f32x4*)&red[2048 + e];
    s += *(const f32x4*)&red[3072 + e];
    half4 o;
#pragma unroll
    for (int i = 0; i < 4; ++i) o[i] = (_Float16)s[i];
    *(half4*)(kvT + (size_t)bid * 1024 + e) = o;
}

// ---- K3: fused softmax(q)@kvT + final conv -> relu -> out ------------------
// R13 structure (9 phases, waves 0..5 PV) + fsw() chunk swizzle on Xt to kill
// the measured 9.4e6-cycle LDS bank conflict (write instrs were 8 lanes/bank).
__global__ __launch_bounds__(512, 2) void k_conv_out(
    const _Float16* __restrict__ q, const _Float16* __restrict__ kvw,
    const _Float16* __restrict__ Cfrag, const float* __restrict__ cbp,
    float* __restrict__ out) {
    __shared__ __align__(16) _Float16 Xt[2][3072];
    __shared__ float Cb[256];

    const int t = threadIdx.x;
    const int bx = blockIdx.x, b = blockIdx.y;
    const int s0 = bx * 96;
    const int n0 = bx * 8;
    const int w = t >> 6, lane = t & 63;
    const int lo = lane & 15, hi = lane >> 4;
    if (t < 64) *(f32x4*)&Cb[t*4] = *(const f32x4*)(cbp + t*4);

    f32x4 acc[4][3] = {};

    const bool pvw = (w < 6);
    const int li0 = w * 2;
    const int qrow = n0 + (lo & 7);
    const float rowmask = (lo < 8) ? 1.f : 0.f;
    const size_t hstep = (size_t)12 * ND_;
    const _Float16* qb_b = q + (size_t)b * 8 * hstep;
    const _Float16* kv_b = kvw + (size_t)b * 98304;

    half8 hq0 = {}, hq1 = {};
    if (pvw) {
        hq0 = *(const half8*)(qb_b + (size_t)li0 * ND_ + (size_t)qrow*32 + hi*8);
        hq1 = *(const half8*)(qb_b + (size_t)(li0+1) * ND_ + (size_t)qrow*32 + hi*8);
    }

    for (int ph = 0; ph <= 8; ++ph) {
        if (ph < 8 && pvw) {
            half8 nq0 = hq0, nq1 = hq1;
            if (ph < 7) {
                nq0 = *(const half8*)(qb_b + (ph+1)*hstep + (size_t)li0 * ND_ + (size_t)qrow*32 + hi*8);
                nq1 = *(const half8*)(qb_b + (ph+1)*hstep + (size_t)(li0+1) * ND_ + (size_t)qrow*32 + hi*8);
            }
            const _Float16* kvh = kv_b + (size_t)ph * 12288;
            _Float16* Xd = Xt[ph & 1];
#pragma unroll
            for (int sub = 0; sub < 2; ++sub) {
                const half8 hq = sub ? hq1 : hq0;
                const int li = li0 + sub;
                float qv[8];
#pragma unroll
                for (int i = 0; i < 8; ++i) qv[i] = (float)hq[i];
                float m8 = fmaxf(fmaxf(fmaxf(qv[0], qv[1]), fmaxf(qv[2], qv[3])),
                                 fmaxf(fmaxf(qv[4], qv[5]), fmaxf(qv[6], qv[7])));
                m8 = fmaxf(m8, __shfl_xor(m8, 16));
                m8 = fmaxf(m8, __shfl_xor(m8, 32));
                const float mS = m8 * SCALE_;
                float ex[8]; float ssum = 0.f;
#pragma unroll
                for (int i = 0; i < 8; ++i) { ex[i] = __expf(qv[i]*SCALE_ - mS); ssum += ex[i]; }
                ssum += __shfl_xor(ssum, 16);
                ssum += __shfl_xor(ssum, 32);
                const float pin = rowmask / ssum;
                half8 af;
#pragma unroll
                for (int i = 0; i < 8; ++i) af[i] = (_Float16)(ex[i] * pin);
                const half8 b0 = *(const half8*)(kvh + li*1024 + lo*32 + hi*8);
                const half8 b1 = *(const half8*)(kvh + li*1024 + (16+lo)*32 + hi*8);
                f32x4 d0 = {}, d1 = {};
                d0 = __builtin_amdgcn_mfma_f32_16x16x32_f16(af, b0, d0, 0, 0, 0);
                d1 = __builtin_amdgcn_mfma_f32_16x16x32_f16(af, b1, d1, 0, 0, 0);
                if (hi < 2) {
#pragma unroll
                    for (int reg = 0; reg < 4; ++reg) {
                        const int sr = (hi*4 + reg)*12 + li;
                        const int cb_ = (sr >> 4)*64 + (sr & 15);
                        const int ca = cb_ + (lo >> 3)*16;
                        const int cc = cb_ + (2 + (lo >> 3))*16;
                        Xd[fsw(ca)*8 + (lo & 7)] = (_Float16)d0[reg];
                        Xd[fsw(cc)*8 + (lo & 7)] = (_Float16)d1[reg];
                    }
                }
            }
            hq0 = nq0; hq1 = nq1;
        }
        if (ph >= 1) {
            const _Float16* Wk = Cfrag + (size_t)(ph - 1) * 8192;
            const _Float16* Xc = Xt[(ph - 1) & 1];
            half8 af2[4], bf[3];
#pragma unroll
            for (int m = 0; m < 4; ++m)
                af2[m] = *(const half8*)(Wk + ((((w>>1)*4 + m)*4 + hi)*16 + lo) * 8);
#pragma unroll
            for (int sf = 0; sf < 3; ++sf) {
                const int rc = ((w & 1)*3 + sf)*64 + hi*16 + lo;
                bf[sf] = *(const half8*)&Xc[fsw(rc)*8];
            }
#pragma unroll
            for (int m = 0; m < 4; ++m)
#pragma unroll
                for (int sf = 0; sf < 3; ++sf)
                    acc[m][sf] = __builtin_amdgcn_mfma_f32_16x16x32_f16(af2[m], bf[sf], acc[m][sf], 0, 0, 0);
        }
        asm volatile("s_waitcnt lgkmcnt(0)" ::: "memory");
        __builtin_amdgcn_s_barrier();
        __builtin_amdgcn_sched_barrier(0);
    }

#pragma unroll
    for (int m = 0; m < 4; ++m) {
        const int o = (w>>1)*64 + m*16 + hi*4;
        const f32x4 bb = *(const f32x4*)&Cb[o];
#pragma unroll
        for (int sf = 0; sf < 3; ++sf) {
            const int s = s0 + (w&1)*48 + sf*16 + lo;
            float* dst = out + (size_t)(b*256 + o)*12288 + s;
#pragma unroll
            for (int i = 0; i < 4; ++i)
                dst[(size_t)i * 12288] = fmaxf(acc[m][sf][i] + bb[i], 0.f);
        }
    }
}

extern "C" void kernel_launch(void* const* d_in, const int* in_sizes, int n_in,
                              void* d_out, int out_size, void* d_ws, size_t ws_size,
                              hipStream_t stream) {
    const float* input = (const float*)d_in[0];
    const float* q_w   = (const float*)d_in[1];
    const float* q_b   = (const float*)d_in[2];
    const float* v_w   = (const float*)d_in[3];
    const float* v_b   = (const float*)d_in[4];
    const float* c_w   = (const float*)d_in[5];
    const float* c_b   = (const float*)d_in[6];
    const float* s_bank= (const float*)d_in[7];
    float* out = (float*)d_out;

    char* ws = (char*)d_ws;
    _Float16* ks16 = (_Float16*)ws;                          // 6,291,456 B (ksT)
    _Float16* qh   = (_Float16*)(ws + 6291456);              // 201,326,592 B
    _Float16* vh   = qh + (size_t)100663296;                 // 201,326,592 B
    _Float16* kvT  = vh + (size_t)100663296;                 // 6,291,456 B
    _Float16* Wfrag= kvT + (size_t)3145728;                  // 262,144 B
    _Float16* Cfrag= Wfrag + (size_t)131072;                 // 131,072 B

    k_prep<<<dim3(96), dim3(256), 0, stream>>>(q_w, v_w, c_w, Wfrag, Cfrag);
    k_key_softmax<<<dim3(HLN_ / 256), dim3(256), 0, stream>>>(s_bank, ks16);
    k_conv_qv<<<dim3(16, 32), dim3(512), 0, stream>>>(input, Wfrag, q_b, v_b, qh, vh);
    k_kv<<<dim3(B_ * H_ * L_), dim3(256), 0, stream>>>(ks16, vh, kvT);
    k_conv_out<<<dim3(128, 32), dim3(512), 0, stream>>>(qh, kvT, Cfrag, c_b, out);
}

// Round 16
// 534.988 us; speedup vs baseline: 1.1889x; 1.0510x over previous
//
#include <hip/hip_runtime.h>

#define B_   32
#define C_   256
#define N_   1024
#define L_   12
#define H_   8
#define DK_  32
#define NL_  12288
#define CNL_ 3145728
#define ND_  32768
#define HLN_ 98304
#define SCALE_ 0.17677669529663687f

typedef _Float16 half8 __attribute__((ext_vector_type(8)));
typedef _Float16 half4 __attribute__((ext_vector_type(4)));
typedef float f32x4 __attribute__((ext_vector_type(4)));

__device__ __forceinline__ int div12(int s) { return (int)(((unsigned)s * 43691u) >> 19); }
// bank-spreading chunk swizzle for conv_out's Xt (bijective, banks spread per instr)
__device__ __forceinline__ int fsw(int c) { return c ^ (((c >> 4) & 1) << 2) ^ ((c >> 6) & 3); }

// ---- P: one-time fp32 -> fp16 weight conversion into FRAGMENT-ORDER layout --
__global__ __launch_bounds__(256) void k_prep(const float* __restrict__ wq,
    const float* __restrict__ wv, const float* __restrict__ cw,
    _Float16* __restrict__ Wfrag, _Float16* __restrict__ Cfrag) {
    const int gid = blockIdx.x * 256 + threadIdx.x;   // grid 96 -> 24576
    if (gid < 16384) {
        const int kb = gid >> 11, r = gid & 2047;
        const int mt = r >> 6, o = (r >> 4) & 3, lo = r & 15;
        const int m = mt * 16 + lo;
        const float* src = (m < 256 ? wq + (size_t)m * 256 : wv + (size_t)(m - 256) * 256)
                           + kb * 32 + o * 8;
        f32x4 a0 = *(const f32x4*)src, a1 = *(const f32x4*)(src + 4);
        half8 h;
#pragma unroll
        for (int i = 0; i < 4; ++i) { h[i] = (_Float16)a0[i]; h[4 + i] = (_Float16)a1[i]; }
        *(half8*)(Wfrag + (size_t)gid * 8) = h;
    } else {
        const int c = gid - 16384;                    // < 8192
        const int kb = c >> 10, r = c & 1023;
        const int mt = r >> 6, o = (r >> 4) & 3, lo = r & 15;
        const int m = mt * 16 + lo;
        const float* src = cw + (size_t)m * 256 + kb * 32 + o * 8;
        f32x4 a0 = *(const f32x4*)src, a1 = *(const f32x4*)(src + 4);
        half8 h;
#pragma unroll
        for (int i = 0; i < 4; ++i) { h[i] = (_Float16)a0[i]; h[4 + i] = (_Float16)a1[i]; }
        *(half8*)(Cfrag + (size_t)c * 8) = h;
    }
}

// ---- K0: softmax over DK -> ksT[hl][x][n]; LDS transpose, coalesced stores --
__global__ __launch_bounds__(256) void k_key_softmax(const float* __restrict__ sb,
                                                     _Float16* __restrict__ ksT) {
    __shared__ _Float16 smT[32 * 260];
    const int t = threadIdx.x;
    const int row = blockIdx.x * 256 + t;
    const f32x4* src = (const f32x4*)(sb + (size_t)row * DK_);
    float v[DK_];
#pragma unroll
    for (int i = 0; i < 8; i++) {
        f32x4 t4 = src[i];
        v[4*i+0] = t4[0]; v[4*i+1] = t4[1]; v[4*i+2] = t4[2]; v[4*i+3] = t4[3];
    }
    float m = v[0];
#pragma unroll
    for (int i = 1; i < DK_; i++) m = fmaxf(m, v[i]);
    float s = 0.f;
#pragma unroll
    for (int i = 0; i < DK_; i++) { v[i] = __expf((v[i] - m) * SCALE_); s += v[i]; }
    const float inv = 1.f / s;
#pragma unroll
    for (int i = 0; i < DK_; i++) smT[i * 260 + t] = (_Float16)(v[i] * inv);
    __syncthreads();
    const int x = t >> 3, off = (t & 7) * 32;
    const int base = blockIdx.x * 256;
    const int hl = base >> 10, nb = base & 1023;
    _Float16* dst = ksT + (size_t)hl * ND_ + (size_t)x * 1024 + nb + off;
    const _Float16* srcT = &smT[x * 260 + off];
#pragma unroll
    for (int k = 0; k < 4; ++k)
        *(half8*)(dst + k * 8) = *(const half8*)(srcT + k * 8);
}

// ------- K1 (R11-best): merged q+v conv; M=512, W in REGISTERS, S=32/iter ---
__global__ __launch_bounds__(512, 2) void k_conv_qv(
    const float* __restrict__ x, const _Float16* __restrict__ Wfrag,
    const float* __restrict__ bqp, const float* __restrict__ bvp,
    _Float16* __restrict__ qh, _Float16* __restrict__ vh)
{
    __shared__ __align__(16) _Float16 Xl[2][8192];

    const int t = threadIdx.x;
    const int sgrp = blockIdx.x;            // 0..15
    const int b = blockIdx.y;
    const int sbase = sgrp * 768;
    const int w = t >> 6, lane = t & 63;
    const int lo = lane & 15, hi = lane >> 4;

    half8 af[8][4];
#pragma unroll
    for (int kb = 0; kb < 8; ++kb)
#pragma unroll
        for (int m = 0; m < 4; ++m)
            af[kb][m] = *(const half8*)(Wfrag +
                ((size_t)kb*2048 + (size_t)(w*4 + m)*64 + lane) * 8);

    const float* bsel = (w >= 4) ? bvp : bqp;
    f32x4 bb[4];
#pragma unroll
    for (int m = 0; m < 4; ++m)
        bb[m] = *(const f32x4*)(bsel + ((w & 3)*4 + m)*16 + hi*4);

    const int xch = t >> 1, xsh = (t & 1) * 8;
    const int g = xch >> 3, elem = xch & 7;
    const int wb = g*128 + elem;
    const int sx = xsh ^ ((g & 7) << 1) ^ (xsh >> 3);
    const float* px = x + (size_t)b * CNL_ + (size_t)xch * NL_ + sbase + xsh;

    const int base_r = hi*128 + ((lo ^ (hi*2) ^ ((lo & 8) >> 3)) << 3);

    f32x4 c0 = *(const f32x4*)px,        c1 = *(const f32x4*)(px + 4);
    f32x4 c2 = *(const f32x4*)(px + 16), c3 = *(const f32x4*)(px + 20);
#pragma unroll
    for (int k = 0; k < 4; ++k) {
        Xl[0][wb + (((k  ) ^ sx) << 3)]        = (_Float16)c0[k];
        Xl[0][wb + (((k+4) ^ sx) << 3)]        = (_Float16)c1[k];
        Xl[0][4096 + wb + (((k  ) ^ sx) << 3)] = (_Float16)c2[k];
        Xl[0][4096 + wb + (((k+4) ^ sx) << 3)] = (_Float16)c3[k];
    }
    c0 = *(const f32x4*)(px + 32); c1 = *(const f32x4*)(px + 36);
    c2 = *(const f32x4*)(px + 48); c3 = *(const f32x4*)(px + 52);

    for (int i = 0; i < 24; ++i) {
        asm volatile("s_waitcnt lgkmcnt(0)" ::: "memory");
        __builtin_amdgcn_s_barrier();
        __builtin_amdgcn_sched_barrier(0);
        const _Float16* Xc = Xl[i & 1];
        f32x4 acc[4][2] = {};
#pragma unroll
        for (int kb = 0; kb < 8; ++kb) {
            const int ro = kb*512 + (base_r ^ ((kb & 1) << 6));
            half8 bf0 = *(const half8*)&Xc[ro];
            half8 bf1 = *(const half8*)&Xc[4096 + ro];
#pragma unroll
            for (int m = 0; m < 4; ++m) {
                acc[m][0] = __builtin_amdgcn_mfma_f32_16x16x32_f16(af[kb][m], bf0, acc[m][0], 0, 0, 0);
                acc[m][1] = __builtin_amdgcn_mfma_f32_16x16x32_f16(af[kb][m], bf1, acc[m][1], 0, 0, 0);
            }
        }
        if (i < 23) {
            _Float16* Xn = Xl[(i + 1) & 1];
#pragma unroll
            for (int k = 0; k < 4; ++k) {
                Xn[wb + (((k  ) ^ sx) << 3)]        = (_Float16)c0[k];
                Xn[wb + (((k+4) ^ sx) << 3)]        = (_Float16)c1[k];
                Xn[4096 + wb + (((k  ) ^ sx) << 3)] = (_Float16)c2[k];
                Xn[4096 + wb + (((k+4) ^ sx) << 3)] = (_Float16)c3[k];
            }
            if (i < 22) {
                const float* p = px + (size_t)(i + 2) * 32;
                c0 = *(const f32x4*)p;        c1 = *(const f32x4*)(p + 4);
                c2 = *(const f32x4*)(p + 16); c3 = *(const f32x4*)(p + 20);
            }
        }
#pragma unroll
        for (int u = 0; u < 2; ++u) {
            const int sg = sbase + i*32 + u*16 + lo;
            const int n = div12(sg), l = sg - n*12;
#pragma unroll
            for (int m = 0; m < 4; ++m) {
                const int o = (w*4 + m)*16 + hi*4;
                const int ol = o & 255;
                _Float16* dst0 = (w >= 4) ? vh : qh;
                half4 hh;
#pragma unroll
                for (int r = 0; r < 4; ++r) hh[r] = (_Float16)fmaxf(acc[m][u][r] + bb[m][r], 0.f);
                *(half4*)(dst0 + ((size_t)(b*8 + (ol >> 5))*12 + l)*ND_ + (size_t)n*32 + (ol & 31)) = hh;
            }
        }
    }
}

// ---- K2: kvT[b,h,l][y][x] = sum_n V[n][y]*K[n][x] via MFMA ------------------
__global__ __launch_bounds__(256) void k_kv(const _Float16* __restrict__ ksT,
    const _Float16* __restrict__ v, _Float16* __restrict__ kvT) {
    __shared__ float red[4096];
    const int bid = blockIdx.x;            // (b*8+h)*12 + l
    const int bh = bid / 12;
    const int l  = bid - bh * 12;
    const int h  = bh & 7;
    const int t = threadIdx.x, w = t >> 6, lane = t & 63;
    const int lo = lane & 15, hi = lane >> 4;
    const _Float16* vb  = v   + (size_t)bid * ND_;
    const _Float16* ksb = ksT + (size_t)(h*12 + l) * ND_;

    f32x4 acc[2][2] = {};
#pragma unroll 2
    for (int c = 0; c < 8; ++c) {
        const int n0 = w*256 + c*32 + hi*8;
        half8 a0, a1;
#pragma unroll
        for (int j = 0; j < 8; ++j) {
            a0[j] = vb[(size_t)(n0 + j)*32 + lo];
            a1[j] = vb[(size_t)(n0 + j)*32 + 16 + lo];
        }
        half8 b0 = *(const half8*)(ksb + (size_t)lo*1024 + n0);
        half8 b1 = *(const half8*)(ksb + (size_t)(16 + lo)*1024 + n0);
        acc[0][0] = __builtin_amdgcn_mfma_f32_16x16x32_f16(a0, b0, acc[0][0], 0, 0, 0);
        acc[0][1] = __builtin_amdgcn_mfma_f32_16x16x32_f16(a0, b1, acc[0][1], 0, 0, 0);
        acc[1][0] = __builtin_amdgcn_mfma_f32_16x16x32_f16(a1, b0, acc[1][0], 0, 0, 0);
        acc[1][1] = __builtin_amdgcn_mfma_f32_16x16x32_f16(a1, b1, acc[1][1], 0, 0, 0);
    }
#pragma unroll
    for (int m = 0; m < 2; ++m)
#pragma unroll
        for (int xm = 0; xm < 2; ++xm)
#pragma unroll
            for (int reg = 0; reg < 4; ++reg)
                red[w*1024 + (m*16 + hi*4 + reg)*32 + xm*16 + lo] = acc[m][xm][reg];
    __syncthreads();
    const int e = t * 4;
    f32x4 s = *(const f32x4*)&red[e];
    s += *(const f32x4*)&red[1024 + e];
    s += *(const f32x4*)&red[2048 + e];
    s += *(const f32x4*)&red[3072 + e];
    half4 o;
#pragma unroll
    for (int i = 0; i < 4; ++i) o[i] = (_Float16)s[i];
    *(half4*)(kvT + (size_t)bid * 1024 + e) = o;
}

// ---- K3: fused softmax(q)@kvT + final conv; 192-spatial tile ---------------
// R13 phase structure, but tile 256x192 (16 n rows): 2048 blocks, half the
// barrier-phases, 48 conv-MFMA/phase/wave, PV uses all 16 A-rows (no rowmask).
__global__ __launch_bounds__(512, 2) void k_conv_out(
    const _Float16* __restrict__ q, const _Float16* __restrict__ kvw,
    const _Float16* __restrict__ Cfrag, const float* __restrict__ cbp,
    float* __restrict__ out) {
    __shared__ __align__(16) _Float16 Xt[2][6144];
    __shared__ float Cb[256];

    const int t = threadIdx.x;
    const int bx = blockIdx.x, b = blockIdx.y;
    const int s0 = bx * 192;
    const int n0 = bx * 16;
    const int w = t >> 6, lane = t & 63;
    const int lo = lane & 15, hi = lane >> 4;
    if (t < 64) *(f32x4*)&Cb[t*4] = *(const f32x4*)(cbp + t*4);

    f32x4 acc[4][6] = {};

    const bool pvw = (w < 6);
    const int li0 = w * 2;
    const int qrow = n0 + lo;               // 16 distinct rows — full A-frag
    const size_t hstep = (size_t)12 * ND_;
    const _Float16* qb_b = q + (size_t)b * 8 * hstep;
    const _Float16* kv_b = kvw + (size_t)b * 98304;

    half8 hq0 = {}, hq1 = {};
    if (pvw) {
        hq0 = *(const half8*)(qb_b + (size_t)li0 * ND_ + (size_t)qrow*32 + hi*8);
        hq1 = *(const half8*)(qb_b + (size_t)(li0+1) * ND_ + (size_t)qrow*32 + hi*8);
    }

    for (int ph = 0; ph <= 8; ++ph) {
        if (ph < 8 && pvw) {
            half8 nq0 = hq0, nq1 = hq1;
            if (ph < 7) {
                nq0 = *(const half8*)(qb_b + (ph+1)*hstep + (size_t)li0 * ND_ + (size_t)qrow*32 + hi*8);
                nq1 = *(const half8*)(qb_b + (ph+1)*hstep + (size_t)(li0+1) * ND_ + (size_t)qrow*32 + hi*8);
            }
            const _Float16* kvh = kv_b + (size_t)ph * 12288;
            _Float16* Xd = Xt[ph & 1];
#pragma unroll
            for (int sub = 0; sub < 2; ++sub) {
                const half8 hq = sub ? hq1 : hq0;
                const int li = li0 + sub;
                float qv[8];
#pragma unroll
                for (int i = 0; i < 8; ++i) qv[i] = (float)hq[i];
                float m8 = fmaxf(fmaxf(fmaxf(qv[0], qv[1]), fmaxf(qv[2], qv[3])),
                                 fmaxf(fmaxf(qv[4], qv[5]), fmaxf(qv[6], qv[7])));
                m8 = fmaxf(m8, __shfl_xor(m8, 16));
                m8 = fmaxf(m8, __shfl_xor(m8, 32));
                const float mS = m8 * SCALE_;
                float ex[8]; float ssum = 0.f;
#pragma unroll
                for (int i = 0; i < 8; ++i) { ex[i] = __expf(qv[i]*SCALE_ - mS); ssum += ex[i]; }
                ssum += __shfl_xor(ssum, 16);
                ssum += __shfl_xor(ssum, 32);
                const float pin = 1.f / ssum;
                half8 af;
#pragma unroll
                for (int i = 0; i < 8; ++i) af[i] = (_Float16)(ex[i] * pin);
                const half8 b0 = *(const half8*)(kvh + li*1024 + lo*32 + hi*8);
                const half8 b1 = *(const half8*)(kvh + li*1024 + (16+lo)*32 + hi*8);
                f32x4 d0 = {}, d1 = {};
                d0 = __builtin_amdgcn_mfma_f32_16x16x32_f16(af, b0, d0, 0, 0, 0);
                d1 = __builtin_amdgcn_mfma_f32_16x16x32_f16(af, b1, d1, 0, 0, 0);
#pragma unroll
                for (int reg = 0; reg < 4; ++reg) {
                    const int sr = (hi*4 + reg)*12 + li;       // 0..191
                    const int cb_ = (sr >> 4)*64 + (sr & 15);
                    const int ca = cb_ + (lo >> 3)*16;
                    const int cc = cb_ + (2 + (lo >> 3))*16;
                    Xd[fsw(ca)*8 + (lo & 7)] = (_Float16)d0[reg];
                    Xd[fsw(cc)*8 + (lo & 7)] = (_Float16)d1[reg];
                }
            }
            hq0 = nq0; hq1 = nq1;
        }
        if (ph >= 1) {
            const _Float16* Wk = Cfrag + (size_t)(ph - 1) * 8192;
            const _Float16* Xc = Xt[(ph - 1) & 1];
            half8 af2[4], bf[6];
#pragma unroll
            for (int m = 0; m < 4; ++m)
                af2[m] = *(const half8*)(Wk + ((((w>>1)*4 + m)*4 + hi)*16 + lo) * 8);
#pragma unroll
            for (int sf = 0; sf < 6; ++sf) {
                const int rc = ((w & 1)*6 + sf)*64 + hi*16 + lo;
                bf[sf] = *(const half8*)&Xc[fsw(rc)*8];
            }
#pragma unroll
            for (int m = 0; m < 4; ++m)
#pragma unroll
                for (int sf = 0; sf < 6; ++sf)
                    acc[m][sf] = __builtin_amdgcn_mfma_f32_16x16x32_f16(af2[m], bf[sf], acc[m][sf], 0, 0, 0);
        }
        asm volatile("s_waitcnt lgkmcnt(0)" ::: "memory");
        __builtin_amdgcn_s_barrier();
        __builtin_amdgcn_sched_barrier(0);
    }

#pragma unroll
    for (int m = 0; m < 4; ++m) {
        const int o = (w>>1)*64 + m*16 + hi*4;
        const f32x4 bb = *(const f32x4*)&Cb[o];
#pragma unroll
        for (int sf = 0; sf < 6; ++sf) {
            const int s = s0 + (w&1)*96 + sf*16 + lo;
            float* dst = out + (size_t)(b*256 + o)*12288 + s;
#pragma unroll
            for (int i = 0; i < 4; ++i)
                dst[(size_t)i * 12288] = fmaxf(acc[m][sf][i] + bb[i], 0.f);
        }
    }
}

extern "C" void kernel_launch(void* const* d_in, const int* in_sizes, int n_in,
                              void* d_out, int out_size, void* d_ws, size_t ws_size,
                              hipStream_t stream) {
    const float* input = (const float*)d_in[0];
    const float* q_w   = (const float*)d_in[1];
    const float* q_b   = (const float*)d_in[2];
    const float* v_w   = (const float*)d_in[3];
    const float* v_b   = (const float*)d_in[4];
    const float* c_w   = (const float*)d_in[5];
    const float* c_b   = (const float*)d_in[6];
    const float* s_bank= (const float*)d_in[7];
    float* out = (float*)d_out;

    char* ws = (char*)d_ws;
    _Float16* ks16 = (_Float16*)ws;                          // 6,291,456 B (ksT)
    _Float16* qh   = (_Float16*)(ws + 6291456);              // 201,326,592 B
    _Float16* vh   = qh + (size_t)100663296;                 // 201,326,592 B
    _Float16* kvT  = vh + (size_t)100663296;                 // 6,291,456 B
    _Float16* Wfrag= kvT + (size_t)3145728;                  // 262,144 B
    _Float16* Cfrag= Wfrag + (size_t)131072;                 // 131,072 B

    k_prep<<<dim3(96), dim3(256), 0, stream>>>(q_w, v_w, c_w, Wfrag, Cfrag);
    k_key_softmax<<<dim3(HLN_ / 256), dim3(256), 0, stream>>>(s_bank, ks16);
    k_conv_qv<<<dim3(16, 32), dim3(512), 0, stream>>>(input, Wfrag, q_b, v_b, qh, vh);
    k_kv<<<dim3(B_ * H_ * L_), dim3(256), 0, stream>>>(ks16, vh, kvT);
    k_conv_out<<<dim3(64, 32), dim3(512), 0, stream>>>(qh, kvT, Cfrag, c_b, out);
}